// Round 6
// baseline (79.658 us; speedup 1.0000x reference)
//
#include <hip/hip_runtime.h>
#include <hip/hip_cooperative_groups.h>

// CenterLoss reduced form (cross term discarded in the reference):
//   loss = (1/B) * sum_i clip(||x_i||^2 + ||centers[y_i]||^2, 1e-12, 1e12)
//          + (C-1) * 1e-12        // clip floor on the B*(C-1) zero entries
//
// Fused single cooperative kernel:
//  - 1024 blocks x 256 thr = 4096 waves; each wave owns exactly 4 rows
//    (compile-time trip count -> full unroll -> 4 independent y->center
//    gather chains in flight, no serial latency chain).
//  - per row: 64 lanes x float2 of x-row + gathered center-row, ONE fused
//    f32 butterfly (s+c combined, 6 shfl_xor) -> clip -> f64 wave acc.
//  - block partial -> grid.sync() -> block 0, wave 0 reduces 1024 doubles
//    (16/lane, 6 double-shuffles, no barriers). Fixed order everywhere ->
//    bit-deterministic across graph replays.

#define DIM 128
#define BATCH 16384
#define NUM_CLASSES 10000
#define GRID 1024
#define WAVES (GRID * 4)          // 4096
#define ROWS_PER_WAVE (BATCH / WAVES)  // 4

namespace cg = cooperative_groups;

__global__ __launch_bounds__(256) void centerloss_fused(
    const float* __restrict__ x,
    const float* __restrict__ centers,
    const int* __restrict__ y,
    double* __restrict__ partials,
    float* __restrict__ out)
{
    const int lane = threadIdx.x & 63;
    const int wib  = threadIdx.x >> 6;              // wave in block [0,4)
    const int gwave = blockIdx.x * 4 + wib;         // [0, 4096)

    double acc = 0.0;
    #pragma unroll
    for (int k = 0; k < ROWS_PER_WAVE; ++k) {
        const int row = gwave + k * WAVES;
        const int cls = y[row];                      // 4 independent chains after unroll
        const float2 xv = *reinterpret_cast<const float2*>(x + (size_t)row * DIM + lane * 2);
        const float2 cv = *reinterpret_cast<const float2*>(centers + (size_t)cls * DIM + lane * 2);
        float t = xv.x * xv.x + xv.y * xv.y + cv.x * cv.x + cv.y * cv.y;
        #pragma unroll
        for (int off = 32; off > 0; off >>= 1)
            t += __shfl_xor(t, off, 64);             // all lanes hold row total
        if (lane == 0) {
            double dv = fmin(fmax((double)t, 1e-12), 1e12);   // clip (no-op here)
            acc += dv;
        }
    }

    __shared__ double lds[4];
    if (lane == 0) lds[wib] = acc;
    __syncthreads();
    if (threadIdx.x == 0) {
        partials[blockIdx.x] = (lds[0] + lds[1]) + (lds[2] + lds[3]);
        __threadfence();                             // publish before grid sync
    }

    cg::this_grid().sync();

    if (blockIdx.x == 0 && threadIdx.x < 64) {
        double s = 0.0;
        #pragma unroll
        for (int i = 0; i < GRID / 64; ++i)          // 16 independent loads, fixed order
            s += partials[lane + i * 64];
        #pragma unroll
        for (int off = 32; off > 0; off >>= 1)
            s += __shfl_xor(s, off, 64);
        if (lane == 0)
            out[0] = (float)(s / (double)BATCH
                             + (double)(NUM_CLASSES - 1) * 1e-12);
    }
}

extern "C" void kernel_launch(void* const* d_in, const int* in_sizes, int n_in,
                              void* d_out, int out_size, void* d_ws, size_t ws_size,
                              hipStream_t stream)
{
    const float* x        = (const float*)d_in[0];
    const float* centers  = (const float*)d_in[1];
    const int*   y        = (const int*)d_in[2];
    float*       out      = (float*)d_out;
    double*      partials = (double*)d_ws;           // GRID doubles = 8 KiB

    void* args[] = { (void*)&x, (void*)&centers, (void*)&y,
                     (void*)&partials, (void*)&out };
    hipLaunchCooperativeKernel((const void*)centerloss_fused,
                               dim3(GRID), dim3(256), args, 0, stream);
}

// Round 15
// 12.099 us; speedup vs baseline: 6.5837x; 6.5837x over previous
//
#include <hip/hip_runtime.h>

// CenterLoss reduced form (cross term discarded in the reference):
//   loss = (1/B) * sum_i clip(||x_i||^2 + ||centers[y_i]||^2, 1e-12, 1e12)
//          + (C-1) * 1e-12        // clip floor on the B*(C-1) zero entries
//
// Round 6 post-mortem: cooperative grid.sync() cost ~50us on gfx950 (software
// barrier across 8 non-coherent XCD L2s). Back to 2 kernels.
//
// Main: 2048 blocks x 256. Each wave handles TWO rows via float4:
//   lane l loads x[rowpair*256 + 4l] -> one contiguous 1KB segment = 2 rows
//   (lanes 0-31 = row 2*rp, lanes 32-63 = row 2*rp+1). Each half-wave gathers
//   its center row (512B contiguous). 5-step xor butterfly within each half
//   -> per-row sum -> clip -> f64 -> 8 LDS doubles -> block partial.
// Final: ONE wave, 2048 partials = 32 loads/lane + 6 double shuffles, no
// barriers. All fixed-order -> bit-deterministic across graph replays.

#define DIM 128
#define BATCH 16384
#define NUM_CLASSES 10000
#define MAIN_BLOCKS 2048   // x4 waves x2 rows = 16384 rows exactly

__global__ __launch_bounds__(256) void centerloss_main(
    const float* __restrict__ x,
    const float* __restrict__ centers,
    const int* __restrict__ y,
    double* __restrict__ partials)
{
    const int lane = threadIdx.x & 63;
    const int wib  = threadIdx.x >> 6;                 // wave in block [0,4)
    const int half = lane >> 5;                        // 0: even row, 1: odd row
    const int rowpair = blockIdx.x * 4 + wib;          // [0, 8192)
    const int row = rowpair * 2 + half;                // this half-wave's row

    const int cls = y[row];                            // 2 values/wave, coalesced
    const float4 xv = *reinterpret_cast<const float4*>(
        x + (size_t)rowpair * (2 * DIM) + lane * 4);   // contiguous 1KB: 2 rows
    const float4 cv = *reinterpret_cast<const float4*>(
        centers + (size_t)cls * DIM + (lane & 31) * 4);

    float t = xv.x * xv.x + xv.y * xv.y + xv.z * xv.z + xv.w * xv.w
            + cv.x * cv.x + cv.y * cv.y + cv.z * cv.z + cv.w * cv.w;
    #pragma unroll
    for (int off = 16; off > 0; off >>= 1)
        t += __shfl_xor(t, off, 64);                   // stays within 32-lane half

    __shared__ double lds[8];
    if ((lane & 31) == 0)
        lds[wib * 2 + half] = fmin(fmax((double)t, 1e-12), 1e12);
    __syncthreads();
    if (threadIdx.x == 0) {
        double s = 0.0;
        #pragma unroll
        for (int i = 0; i < 8; ++i) s += lds[i];       // fixed order
        partials[blockIdx.x] = s;
    }
}

__global__ __launch_bounds__(64) void centerloss_final(
    const double* __restrict__ partials, float* __restrict__ out)
{
    const int lane = threadIdx.x;                      // single wave
    double s = 0.0;
    #pragma unroll
    for (int i = 0; i < MAIN_BLOCKS / 64; ++i)         // 32 independent loads
        s += partials[lane + i * 64];
    #pragma unroll
    for (int off = 32; off > 0; off >>= 1)
        s += __shfl_xor(s, off, 64);
    if (lane == 0)
        out[0] = (float)(s / (double)BATCH
                         + (double)(NUM_CLASSES - 1) * 1e-12);
}

extern "C" void kernel_launch(void* const* d_in, const int* in_sizes, int n_in,
                              void* d_out, int out_size, void* d_ws, size_t ws_size,
                              hipStream_t stream)
{
    const float* x        = (const float*)d_in[0];
    const float* centers  = (const float*)d_in[1];
    const int*   y        = (const int*)d_in[2];
    float*       out      = (float*)d_out;
    double*      partials = (double*)d_ws;             // 2048 doubles = 16 KiB

    centerloss_main<<<MAIN_BLOCKS, 256, 0, stream>>>(x, centers, y, partials);
    centerloss_final<<<1, 64, 0, stream>>>(partials, out);
}